// Round 3
// baseline (82915.619 us; speedup 1.0000x reference)
//
#include <hip/hip_runtime.h>
#include <math.h>
#include <stdint.h>

// ---------------------------------------------------------------------------
// InvertedCognitionModel: B=8, T=2048, D=512, KQ=32, K=4
//   router (fp32 sim + top4, fused) -> gather-mean -> FFN+LN (bf16 MFMA)
//   -> serial gated memory scan (persistent, LDS-resident weights, 2-round
//      flag exchange per step) -> output GEMV
// ---------------------------------------------------------------------------

using bf16x8 = __attribute__((ext_vector_type(8))) short;
using f32x4v = __attribute__((ext_vector_type(4))) float;
typedef unsigned long long ull;

__device__ inline unsigned short f2b(float f) {
  union { float f; unsigned int u; } v; v.f = f;
  unsigned int r = v.u + 0x7fffu + ((v.u >> 16) & 1u);   // RNE
  return (unsigned short)(r >> 16);
}

__device__ inline float gelu_f(float x) {
  return 0.5f * x * (1.0f + erff(x * 0.70710678118654752f));
}

// sorted-descending top-4 insert, tie-break lower index first
__device__ inline void ins4(float v, int i,
                            float& v0, int& i0, float& v1, int& i1,
                            float& v2, int& i2, float& v3, int& i3) {
  bool b0 = (v > v0) || (v == v0 && i < i0);
  bool b1 = (v > v1) || (v == v1 && i < i1);
  bool b2 = (v > v2) || (v == v2 && i < i2);
  bool b3 = (v > v3) || (v == v3 && i < i3);
  float nv3 = b2 ? v2 : (b3 ? v : v3); int ni3 = b2 ? i2 : (b3 ? i : i3);
  float nv2 = b1 ? v1 : (b2 ? v : v2); int ni2 = b1 ? i1 : (b2 ? i : i2);
  float nv1 = b0 ? v0 : (b1 ? v : v1); int ni1 = b0 ? i0 : (b1 ? i : i1);
  float nv0 = b0 ? v  : v0;            int ni0 = b0 ? i  : i0;
  v0=nv0; i0=ni0; v1=nv1; i1=ni1; v2=nv2; i2=ni2; v3=nv3; i3=ni3;
}

// ---------------- prep kernels ----------------

__global__ __launch_bounds__(256)
void wqk_kernel(const float* __restrict__ Wq, const float* __restrict__ Wk,
                float* __restrict__ wqk) {
  int id = blockIdx.x * 256 + threadIdx.x;        // < 512*64
  int d = id >> 6, c = id & 63;
  wqk[id] = (c < 32) ? Wq[d * 32 + c] : Wk[d * 32 + (c - 32)];
}

// dst[n][k] = bf16(src[k][n]); src is [>=K x N] row-major, dst [N x K]
__global__ __launch_bounds__(256)
void transpose_bf16_kernel(const float* __restrict__ src,
                           unsigned short* __restrict__ dst, int K, int N) {
  __shared__ float tile[32][33];
  int bk = blockIdx.x << 5, bn = blockIdx.y << 5;
  int c = threadIdx.x & 31, r8 = threadIdx.x >> 5;
  for (int r = r8; r < 32; r += 8) tile[r][c] = src[(size_t)(bk + r) * N + bn + c];
  __syncthreads();
  for (int r = r8; r < 32; r += 8) dst[(size_t)(bn + r) * K + bk + c] = f2b(tile[c][r]);
}

// ---------------- router ----------------

// q|k projection: qkout[b,t,0:32]=q, [32:64]=k (fp32, biases included)
__global__ __launch_bounds__(256)
void qk_kernel(const float* __restrict__ x, const float* __restrict__ wqk,
               const float* __restrict__ bq, const float* __restrict__ bk,
               float* __restrict__ qkout) {
  __shared__ float xs[16][512];
  int tid = threadIdx.x;
  int b = blockIdx.x >> 7;
  int t0 = (blockIdx.x & 127) << 4;
  const float* xb = x + ((size_t)(b * 2048 + t0)) * 512;
#pragma unroll
  for (int i = 0; i < 8; ++i) {
    int f = i * 256 + tid;
    int r = f >> 7, c4 = f & 127;
    *(float4*)&xs[r][c4 * 4] = *(const float4*)&xb[(size_t)r * 512 + c4 * 4];
  }
  __syncthreads();
  int c = tid & 63, r4 = tid >> 6;
  float a0 = 0.f, a1 = 0.f, a2 = 0.f, a3 = 0.f;
#pragma unroll 4
  for (int d = 0; d < 512; ++d) {
    float w = wqk[d * 64 + c];
    a0 += xs[r4][d] * w;
    a1 += xs[r4 + 4][d] * w;
    a2 += xs[r4 + 8][d] * w;
    a3 += xs[r4 + 12][d] * w;
  }
  float bias = (c < 32) ? bq[c] : bk[c - 32];
  size_t base = ((size_t)(b * 2048 + t0)) * 64 + c;
  qkout[base + (size_t)r4 * 64] = a0 + bias;
  qkout[base + (size_t)(r4 + 4) * 64] = a1 + bias;
  qkout[base + (size_t)(r4 + 8) * 64] = a2 + bias;
  qkout[base + (size_t)(r4 + 12) * 64] = a3 + bias;
}

// fused sim + top-4: block = 16 query rows; never materializes sim
__global__ __launch_bounds__(256)
void topk_kernel(const float* __restrict__ qkb, int* __restrict__ idxout) {
  __shared__ float qs[16][36];
  __shared__ float ks[128][36];
  __shared__ float mv[16][16][4];
  __shared__ int   mi[16][16][4];
  int tid = threadIdx.x;
  int b = blockIdx.x >> 7;
  int t0 = (blockIdx.x & 127) << 4;
  const float* qb = qkb + ((size_t)b * 2048) * 64;
  if (tid < 128) {
    int r = tid >> 3, c4 = tid & 7;
    *(float4*)&qs[r][c4 * 4] = *(const float4*)&qb[(size_t)(t0 + r) * 64 + c4 * 4];
  }
  __syncthreads();
  int tl = tid >> 4, sl = tid & 15;
  float qv[32];
#pragma unroll
  for (int kk = 0; kk < 32; ++kk) qv[kk] = qs[tl][kk];
  float v0 = -INFINITY, v1 = -INFINITY, v2 = -INFINITY, v3 = -INFINITY;
  int i0 = 0x7fffffff, i1 = 0x7fffffff, i2 = 0x7fffffff, i3 = 0x7fffffff;
  for (int s0 = 0; s0 < 2048; s0 += 128) {
    __syncthreads();
#pragma unroll
    for (int p = 0; p < 4; ++p) {
      int f = p * 256 + tid;
      int r = f >> 3, c4 = f & 7;
      *(float4*)&ks[r][c4 * 4] =
          *(const float4*)&qb[(size_t)(s0 + r) * 64 + 32 + c4 * 4];
    }
    __syncthreads();
#pragma unroll
    for (int j = 0; j < 8; ++j) {
      int srow = j * 16 + sl;
      float accv = 0.f;
#pragma unroll
      for (int k4 = 0; k4 < 8; ++k4) {
        float4 kv = *(const float4*)&ks[srow][k4 * 4];
        accv += qv[k4 * 4 + 0] * kv.x + qv[k4 * 4 + 1] * kv.y +
                qv[k4 * 4 + 2] * kv.z + qv[k4 * 4 + 3] * kv.w;
      }
      ins4(accv, s0 + srow, v0, i0, v1, i1, v2, i2, v3, i3);
    }
  }
  mv[tl][sl][0] = v0; mv[tl][sl][1] = v1; mv[tl][sl][2] = v2; mv[tl][sl][3] = v3;
  mi[tl][sl][0] = i0; mi[tl][sl][1] = i1; mi[tl][sl][2] = i2; mi[tl][sl][3] = i3;
  __syncthreads();
  if (tid < 16) {
    float w0 = -INFINITY, w1 = -INFINITY, w2 = -INFINITY, w3 = -INFINITY;
    int a0 = 0x7fffffff, a1 = 0x7fffffff, a2 = 0x7fffffff, a3 = 0x7fffffff;
    for (int ss = 0; ss < 16; ++ss)
#pragma unroll
      for (int q = 0; q < 4; ++q)
        ins4(mv[tid][ss][q], mi[tid][ss][q], w0, a0, w1, a1, w2, a2, w3, a3);
    int4 o; o.x = a0; o.y = a1; o.z = a2; o.w = a3;
    *(int4*)&idxout[((size_t)(b * 2048 + t0 + tid)) * 4] = o;
  }
}

__global__ __launch_bounds__(128)
void gather_kernel(const float* __restrict__ x, const int* __restrict__ idx,
                   float* __restrict__ gf, unsigned short* __restrict__ gb) {
  int bt = blockIdx.x;
  int b = bt >> 11;
  const int4 iv = *(const int4*)&idx[(size_t)bt * 4];
  int tid = threadIdx.x;
  const float* xb = x + ((size_t)b * 2048) * 512;
  float4 p0 = *(const float4*)&xb[(size_t)iv.x * 512 + tid * 4];
  float4 p1 = *(const float4*)&xb[(size_t)iv.y * 512 + tid * 4];
  float4 p2 = *(const float4*)&xb[(size_t)iv.z * 512 + tid * 4];
  float4 p3 = *(const float4*)&xb[(size_t)iv.w * 512 + tid * 4];
  float4 m;
  m.x = (p0.x + p1.x + p2.x + p3.x) * 0.25f;
  m.y = (p0.y + p1.y + p2.y + p3.y) * 0.25f;
  m.z = (p0.z + p1.z + p2.z + p3.z) * 0.25f;
  m.w = (p0.w + p1.w + p2.w + p3.w) * 0.25f;
  *(float4*)&gf[(size_t)bt * 512 + tid * 4] = m;
  ushort4 u; u.x = f2b(m.x); u.y = f2b(m.y); u.z = f2b(m.z); u.w = f2b(m.w);
  *(ushort4*)&gb[(size_t)bt * 512 + tid * 4] = u;
}

// ---------------- MFMA GEMM: C = A[MxK] * Bt[NxK]^T (+bias, epilogues) ------
// MODE 0: out bf16 = gelu(acc+bias)   MODE 1: out f32 = acc+bias+resid
// MODE 2: out f32 = acc+bias

template <int MODE>
__global__ __launch_bounds__(256, 2)
void gemm_bf16_k(const unsigned short* __restrict__ A,
                 const unsigned short* __restrict__ Bt,
                 const float* __restrict__ bias,
                 const float* __restrict__ resid,
                 void* __restrict__ outp, int M, int N, int K) {
  __shared__ unsigned short sA[128 * 32];
  __shared__ unsigned short sB[128 * 32];
  const int tid = threadIdx.x;
  const int lane = tid & 63, wave = tid >> 6;
  const int m0 = blockIdx.x * 128, n0 = blockIdx.y * 128;
  const int col16 = lane & 15, quad = lane >> 4;
  const int wm = wave >> 1, wn = wave & 1;
  f32x4v acc[4][4];
#pragma unroll
  for (int i = 0; i < 4; ++i)
#pragma unroll
    for (int j = 0; j < 4; ++j) {
      f32x4v z = {0.f, 0.f, 0.f, 0.f};
      acc[i][j] = z;
    }
  const int nkt = K >> 5;
  for (int kt = 0; kt < nkt; ++kt) {
    const int k0 = kt << 5;
#pragma unroll
    for (int p = 0; p < 2; ++p) {
      int f = p * 256 + tid;
      int row = f >> 2, q4 = f & 3;
      *(uint4*)&sA[row * 32 + q4 * 8] =
          *(const uint4*)(A + (size_t)(m0 + row) * K + k0 + q4 * 8);
      *(uint4*)&sB[row * 32 + q4 * 8] =
          *(const uint4*)(Bt + (size_t)(n0 + row) * K + k0 + q4 * 8);
    }
    __syncthreads();
    bf16x8 af[4], bfr[4];
#pragma unroll
    for (int i = 0; i < 4; ++i)
      af[i] = *(const bf16x8*)&sA[(wm * 64 + i * 16 + col16) * 32 + quad * 8];
#pragma unroll
    for (int j = 0; j < 4; ++j)
      bfr[j] = *(const bf16x8*)&sB[(wn * 64 + j * 16 + col16) * 32 + quad * 8];
#pragma unroll
    for (int i = 0; i < 4; ++i)
#pragma unroll
      for (int j = 0; j < 4; ++j)
        acc[i][j] = __builtin_amdgcn_mfma_f32_16x16x32_bf16(af[i], bfr[j],
                                                            acc[i][j], 0, 0, 0);
    __syncthreads();
  }
  float* outf = (float*)outp;
  unsigned short* outb = (unsigned short*)outp;
#pragma unroll
  for (int i = 0; i < 4; ++i)
#pragma unroll
    for (int j = 0; j < 4; ++j) {
      int col = n0 + wn * 64 + j * 16 + col16;
      float bs = bias[col];
#pragma unroll
      for (int r = 0; r < 4; ++r) {
        int row = m0 + wm * 64 + i * 16 + quad * 4 + r;
        float v = acc[i][j][r] + bs;
        if (MODE == 0) {
          outb[(size_t)row * N + col] = f2b(gelu_f(v));
        } else if (MODE == 1) {
          outf[(size_t)row * N + col] = v + resid[(size_t)row * N + col];
        } else {
          outf[(size_t)row * N + col] = v;
        }
      }
    }
}

// ---------------- LayerNorm (row-wise, fp32 -> bf16) ----------------

__global__ __launch_bounds__(128)
void ln_kernel(const float* __restrict__ ypre, const float* __restrict__ lg,
               const float* __restrict__ lb, unsigned short* __restrict__ yb) {
  int row = blockIdx.x, tid = threadIdx.x;
  float4 v = *(const float4*)&ypre[(size_t)row * 512 + tid * 4];
  float s = v.x + v.y + v.z + v.w;
  float sq = v.x * v.x + v.y * v.y + v.z * v.z + v.w * v.w;
#pragma unroll
  for (int off = 1; off < 64; off <<= 1) {
    s += __shfl_xor(s, off, 64);
    sq += __shfl_xor(sq, off, 64);
  }
  __shared__ float red[4];
  if ((tid & 63) == 0) { red[(tid >> 6) * 2] = s; red[(tid >> 6) * 2 + 1] = sq; }
  __syncthreads();
  float S = red[0] + red[2], SQ = red[1] + red[3];
  float mu = S * (1.f / 512.f);
  float var = SQ * (1.f / 512.f) - mu * mu;
  float rstd = rsqrtf(var + 1e-5f);
  float4 g4 = *(const float4*)&lg[tid * 4];
  float4 b4 = *(const float4*)&lb[tid * 4];
  ushort4 u;
  u.x = f2b((v.x - mu) * rstd * g4.x + b4.x);
  u.y = f2b((v.y - mu) * rstd * g4.y + b4.y);
  u.z = f2b((v.z - mu) * rstd * g4.z + b4.z);
  u.w = f2b((v.w - mu) * rstd * g4.w + b4.w);
  *(ushort4*)&yb[(size_t)row * 512 + tid * 4] = u;
}

// ---------------- System2: persistent serial scan --------------------------
// 8 teams x 32 WGs x 256 thr; blockIdx = g*8 + team (team-per-XCD swizzle).
// WG g owns u-slice [g*32,g*32+32) and mem-slice [g*16,g*16+16).
// LDS-resident fp32 weights (no spill possible):
//   WbT [32 ucols][512 k] stride 516 (66 KB)  — stage1, float4 reads
//   WtS [32 urows][512 d]              (64 KB) — stage2 row-slice: needs only
//                                                this WG's own gelu values!
// Per step: stage1 full-k matvec slice -> gelu(32 local) -> stage2 partial
// prop[512] -> slot write + flagA (tag s+1, parity dbuf) -> reduce 32 slots
// for own 16 mem-cols -> gated update -> mem-slice write + flagB -> read full
// mem. Exact-tag polls; stale cross-launch tags benign (deterministic data).

__global__ __launch_bounds__(256)
void system2_kernel(const float* __restrict__ Wt1, const float* __restrict__ Wt2,
                    const float* __restrict__ bt2, const float* __restrict__ xpart,
                    float* __restrict__ slotbuf, float* __restrict__ membuf,
                    int* __restrict__ flagA, int* __restrict__ flagB,
                    float* __restrict__ memfinal) {
  __shared__ float WbT[32 * 516];   // [j][k], stride 516 for bank spread
  __shared__ float WtS[32 * 512];   // [u][d]
  __shared__ float memS[512];
  __shared__ float parts1[256];     // [c][j] = [8][32]
  __shared__ float red2[256];       // [w][dd] = [16][16]
  __shared__ float guL[32];

  const int t = threadIdx.x;
  const int team = blockIdx.x & 7;
  const int g = blockIdx.x >> 3;          // 0..31
  const int ucol0 = g << 5;
  const int mcol0 = g << 4;

  // ---- load weights into LDS (one-time) ----
  for (int idx = t; idx < 32 * 512; idx += 256) {
    int j = idx & 31, k = idx >> 5;
    WbT[j * 516 + k] = Wt1[(size_t)(512 + k) * 1024 + ucol0 + j];
  }
  for (int idx = t; idx < 32 * 512; idx += 256) {
    int u = idx >> 9, d = idx & 511;
    WtS[u * 512 + d] = Wt2[(size_t)(ucol0 + u) * 512 + d];
  }
  if (t < 512) { /* memS covers 512 with 256 threads: */ }
  memS[t] = 0.f;
  memS[t + 256] = 0.f;
  const float bt2r = (t < 16) ? bt2[mcol0 + t] : 0.f;
  __syncthreads();

  const int j = t & 31, c = t >> 5;        // stage1 roles: col j, k-chunk c(8)
  const float* xp = xpart + (size_t)team * 2048 * 1024 + ucol0;
  float xv = (t < 32) ? xp[t] : 0.f;

  for (int s = 0; s < 2048; ++s) {
    const int par = s & 1;
    float* slot = slotbuf + ((size_t)(par * 8 + team) * 32) * 512;
    float* memb = membuf + (size_t)(par * 8 + team) * 512;
    int* flA = flagA + (par * 8 + team) * 32;
    int* flB = flagB + (par * 8 + team) * 32;
    const int tag = s + 1;

    float xnext = (t < 32 && s < 2047) ? xp[(size_t)(s + 1) * 1024 + t] : 0.f;

    // ---- stage1: u[ucol0+j] partial over k-chunk c (64 k), float4 LDS ----
    {
      const float* wrow = &WbT[j * 516 + c * 64];
      const float* mrow = &memS[c * 64];
      float p1 = 0.f;
#pragma unroll
      for (int i = 0; i < 64; i += 4) {
        float4 wv = *(const float4*)&wrow[i];
        float4 mv = *(const float4*)&mrow[i];
        p1 += wv.x * mv.x + wv.y * mv.y + wv.z * mv.z + wv.w * mv.w;
      }
      parts1[c * 32 + j] = p1;
    }
    __syncthreads();
    if (t < 32) {
      float u = xv;   // xpart includes xt@Wt1[:512] + bt1
#pragma unroll
      for (int cc = 0; cc < 8; ++cc) u += parts1[cc * 32 + t];
      guL[t] = gelu_f(u);
    }
    __syncthreads();

    // ---- stage2: partial prop over this WG's 32 u-rows; 2 cols/thread ----
    {
      const int d2 = t << 1;
      float px = 0.f, py = 0.f;
#pragma unroll
      for (int u = 0; u < 32; ++u) {
        float gv = guL[u];
        float2 wv = *(const float2*)&WtS[u * 512 + d2];
        px += gv * wv.x;
        py += gv * wv.y;
      }
      union { float2 f2; ull u64; } cv;
      cv.f2 = make_float2(px, py);
      __hip_atomic_store((ull*)&slot[g * 512 + d2], cv.u64, __ATOMIC_RELAXED,
                         __HIP_MEMORY_SCOPE_AGENT);
    }
    __builtin_amdgcn_fence(__ATOMIC_RELEASE, "agent");
    __syncthreads();
    if (t == 0)
      __hip_atomic_store(&flA[g], tag, __ATOMIC_RELEASE,
                         __HIP_MEMORY_SCOPE_AGENT);
    // ---- poll A: all 32 slots ready ----
    if (t < 64) {
      int f = (t < 32) ? 0 : tag;
      const int* fp = &flA[t < 32 ? t : 0];
      while (true) {
        if (t < 32 && f != tag)
          f = __hip_atomic_load(fp, __ATOMIC_RELAXED, __HIP_MEMORY_SCOPE_AGENT);
        if (__ballot(f == tag) == ~0ull) break;
        __builtin_amdgcn_s_sleep(1);
      }
    }
    __syncthreads();
    __builtin_amdgcn_fence(__ATOMIC_ACQUIRE, "agent");

    // ---- reduce 32 partials for own 16 mem-cols ----
    {
      const int w = t >> 4, dd = t & 15;
      float v1 = __hip_atomic_load(&slot[w * 512 + mcol0 + dd], __ATOMIC_RELAXED,
                                   __HIP_MEMORY_SCOPE_AGENT);
      float v2 = __hip_atomic_load(&slot[(w + 16) * 512 + mcol0 + dd],
                                   __ATOMIC_RELAXED, __HIP_MEMORY_SCOPE_AGENT);
      red2[w * 16 + dd] = v1 + v2;
    }
    __syncthreads();
    if (t < 16) {
      float prop = bt2r;
#pragma unroll
      for (int w = 0; w < 16; ++w) prop += red2[w * 16 + t];
      float gate = 1.f / (1.f + __expf(-prop));
      float mnew = memS[mcol0 + t] * (1.f - gate) + prop * gate;
      __hip_atomic_store(&memb[mcol0 + t], mnew, __ATOMIC_RELAXED,
                         __HIP_MEMORY_SCOPE_AGENT);
    }
    __builtin_amdgcn_fence(__ATOMIC_RELEASE, "agent");
    __syncthreads();
    if (t == 0)
      __hip_atomic_store(&flB[g], tag, __ATOMIC_RELEASE,
                         __HIP_MEMORY_SCOPE_AGENT);
    // ---- poll B: all 32 mem slices ready ----
    if (t < 64) {
      int f = (t < 32) ? 0 : tag;
      const int* fp = &flB[t < 32 ? t : 0];
      while (true) {
        if (t < 32 && f != tag)
          f = __hip_atomic_load(fp, __ATOMIC_RELAXED, __HIP_MEMORY_SCOPE_AGENT);
        if (__ballot(f == tag) == ~0ull) break;
        __builtin_amdgcn_s_sleep(1);
      }
    }
    __syncthreads();
    __builtin_amdgcn_fence(__ATOMIC_ACQUIRE, "agent");

    // ---- read full mem (512 floats as 256 ull by t<128) ----
    if (t < 128) {
      union { float2 f2; ull u64; } a, b;
      a.u64 = __hip_atomic_load((ull*)&memb[t * 4], __ATOMIC_RELAXED,
                                __HIP_MEMORY_SCOPE_AGENT);
      b.u64 = __hip_atomic_load((ull*)&memb[t * 4 + 2], __ATOMIC_RELAXED,
                                __HIP_MEMORY_SCOPE_AGENT);
      memS[t * 4 + 0] = a.f2.x;
      memS[t * 4 + 1] = a.f2.y;
      memS[t * 4 + 2] = b.f2.x;
      memS[t * 4 + 3] = b.f2.y;
    }
    xv = xnext;
    __syncthreads();
  }

  if (g == 0 && t < 128)
    *(float4*)&memfinal[(size_t)team * 512 + t * 4] = *(float4*)&memS[t * 4];
}

// ---------------- output GEMV ----------------

__global__ __launch_bounds__(256)
void out_gemv_kernel(const float* __restrict__ memf, const float* __restrict__ Wo,
                     const float* __restrict__ bo, float* __restrict__ out) {
  int gid = blockIdx.x * 256 + threadIdx.x;   // 4096 total
  int b = gid >> 9, d = gid & 511;
  const float* mb = memf + (size_t)b * 512;
  float acc = bo[d];
#pragma unroll 8
  for (int k = 0; k < 512; ++k) acc += mb[k] * Wo[(size_t)k * 512 + d];
  out[gid] = acc;
}

// ---------------- launch ----------------

extern "C" void kernel_launch(void* const* d_in, const int* in_sizes, int n_in,
                              void* d_out, int out_size, void* d_ws, size_t ws_size,
                              hipStream_t stream) {
  const float* x   = (const float*)d_in[0];
  const float* Wq  = (const float*)d_in[1];
  const float* bq  = (const float*)d_in[2];
  const float* Wk  = (const float*)d_in[3];
  const float* bk  = (const float*)d_in[4];
  const float* W1  = (const float*)d_in[5];
  const float* b1  = (const float*)d_in[6];
  const float* W2  = (const float*)d_in[7];
  const float* b2  = (const float*)d_in[8];
  const float* lng = (const float*)d_in[9];
  const float* lnb = (const float*)d_in[10];
  const float* Wt1 = (const float*)d_in[11];
  const float* bt1 = (const float*)d_in[12];
  const float* Wt2 = (const float*)d_in[13];
  const float* bt2 = (const float*)d_in[14];
  const float* Wo  = (const float*)d_in[15];
  const float* bo  = (const float*)d_in[16];
  float* out = (float*)d_out;

  char* ws = (char*)d_ws;
  size_t off = 0;
  auto alloc = [&](size_t bytes) -> void* {
    void* p = ws + off;
    off += (bytes + 255) & ~(size_t)255;
    return p;
  };
  float* qk             = (float*)alloc(8ull * 2048 * 64 * 4);
  int* idxb             = (int*)alloc(8ull * 2048 * 4 * 4);
  float* gathf          = (float*)alloc(16384ull * 512 * 4);
  unsigned short* gathb = (unsigned short*)alloc(16384ull * 512 * 2);
  unsigned short* h1b   = (unsigned short*)alloc(16384ull * 1024 * 2);
  float* ypre           = (float*)alloc(16384ull * 512 * 4);
  unsigned short* yb    = (unsigned short*)alloc(16384ull * 512 * 2);
  float* xpart          = (float*)alloc(16384ull * 1024 * 4);
  unsigned short* w1t   = (unsigned short*)alloc(1024ull * 512 * 2);
  unsigned short* w2t   = (unsigned short*)alloc(512ull * 1024 * 2);
  unsigned short* wt1t  = (unsigned short*)alloc(1024ull * 512 * 2);
  float* wqkb           = (float*)alloc(512ull * 64 * 4);
  float* slotbuf        = (float*)alloc(2ull * 8 * 32 * 512 * 4);  // 1 MB
  float* membuf         = (float*)alloc(2ull * 8 * 512 * 4);
  int* flagA            = (int*)alloc(2ull * 8 * 32 * 4);
  int* flagB            = (int*)alloc(2ull * 8 * 32 * 4);
  float* memf           = (float*)alloc(8ull * 512 * 4);
  if (off > ws_size) return;  // workspace too small -> visible bench failure

  wqk_kernel<<<128, 256, 0, stream>>>(Wq, Wk, wqkb);
  transpose_bf16_kernel<<<dim3(16, 32), 256, 0, stream>>>(W1, w1t, 512, 1024);
  transpose_bf16_kernel<<<dim3(32, 16), 256, 0, stream>>>(W2, w2t, 1024, 512);
  transpose_bf16_kernel<<<dim3(16, 32), 256, 0, stream>>>(Wt1, wt1t, 512, 1024);

  qk_kernel<<<1024, 256, 0, stream>>>(x, wqkb, bq, bk, qk);
  topk_kernel<<<1024, 256, 0, stream>>>(qk, idxb);
  gather_kernel<<<16384, 128, 0, stream>>>(x, idxb, gathf, gathb);

  gemm_bf16_k<0><<<dim3(128, 8), 256, 0, stream>>>(gathb, w1t, b1, nullptr, h1b,
                                                   16384, 1024, 512);
  gemm_bf16_k<1><<<dim3(128, 4), 256, 0, stream>>>(h1b, w2t, b2, gathf, ypre,
                                                   16384, 512, 1024);
  ln_kernel<<<16384, 128, 0, stream>>>(ypre, lng, lnb, yb);
  gemm_bf16_k<2><<<dim3(128, 8), 256, 0, stream>>>(yb, wt1t, bt1, nullptr, xpart,
                                                   16384, 1024, 512);

  system2_kernel<<<256, 256, 0, stream>>>(Wt1, Wt2, bt2, xpart, slotbuf, membuf,
                                          flagA, flagB, memf);
  out_gemv_kernel<<<16, 256, 0, stream>>>(memf, Wo, bo, out);
}

// Round 4
// 7995.824 us; speedup vs baseline: 10.3699x; 10.3699x over previous
//
#include <hip/hip_runtime.h>
#include <math.h>
#include <stdint.h>

// ---------------------------------------------------------------------------
// InvertedCognitionModel: B=8, T=2048, D=512, KQ=32, K=4
//   router (fp32 sim + top4, fused) -> gather-mean -> FFN+LN (bf16 MFMA)
//   -> serial gated memory scan (persistent, LDS weights, FENCE-FREE
//      relaxed-atomic flag exchange; ordering = syncthreads vmcnt drain)
//   -> output GEMV
// ---------------------------------------------------------------------------

using bf16x8 = __attribute__((ext_vector_type(8))) short;
using f32x4v = __attribute__((ext_vector_type(4))) float;
typedef unsigned long long ull;

__device__ inline unsigned short f2b(float f) {
  union { float f; unsigned int u; } v; v.f = f;
  unsigned int r = v.u + 0x7fffu + ((v.u >> 16) & 1u);   // RNE
  return (unsigned short)(r >> 16);
}

__device__ inline float gelu_f(float x) {
  return 0.5f * x * (1.0f + erff(x * 0.70710678118654752f));
}

// sorted-descending top-4 insert, tie-break lower index first
__device__ inline void ins4(float v, int i,
                            float& v0, int& i0, float& v1, int& i1,
                            float& v2, int& i2, float& v3, int& i3) {
  bool b0 = (v > v0) || (v == v0 && i < i0);
  bool b1 = (v > v1) || (v == v1 && i < i1);
  bool b2 = (v > v2) || (v == v2 && i < i2);
  bool b3 = (v > v3) || (v == v3 && i < i3);
  float nv3 = b2 ? v2 : (b3 ? v : v3); int ni3 = b2 ? i2 : (b3 ? i : i3);
  float nv2 = b1 ? v1 : (b2 ? v : v2); int ni2 = b1 ? i1 : (b2 ? i : i2);
  float nv1 = b0 ? v0 : (b1 ? v : v1); int ni1 = b0 ? i0 : (b1 ? i : i1);
  float nv0 = b0 ? v  : v0;            int ni0 = b0 ? i  : i0;
  v0=nv0; i0=ni0; v1=nv1; i1=ni1; v2=nv2; i2=ni2; v3=nv3; i3=ni3;
}

// ---------------- prep kernels ----------------

__global__ __launch_bounds__(256)
void wqk_kernel(const float* __restrict__ Wq, const float* __restrict__ Wk,
                float* __restrict__ wqk) {
  int id = blockIdx.x * 256 + threadIdx.x;        // < 512*64
  int d = id >> 6, c = id & 63;
  wqk[id] = (c < 32) ? Wq[d * 32 + c] : Wk[d * 32 + (c - 32)];
}

// dst[n][k] = bf16(src[k][n]); src is [>=K x N] row-major, dst [N x K]
__global__ __launch_bounds__(256)
void transpose_bf16_kernel(const float* __restrict__ src,
                           unsigned short* __restrict__ dst, int K, int N) {
  __shared__ float tile[32][33];
  int bk = blockIdx.x << 5, bn = blockIdx.y << 5;
  int c = threadIdx.x & 31, r8 = threadIdx.x >> 5;
  for (int r = r8; r < 32; r += 8) tile[r][c] = src[(size_t)(bk + r) * N + bn + c];
  __syncthreads();
  for (int r = r8; r < 32; r += 8) dst[(size_t)(bn + r) * K + bk + c] = f2b(tile[c][r]);
}

// ---------------- router ----------------

// q|k projection: qkout[b,t,0:32]=q, [32:64]=k (fp32, biases included)
__global__ __launch_bounds__(256)
void qk_kernel(const float* __restrict__ x, const float* __restrict__ wqk,
               const float* __restrict__ bq, const float* __restrict__ bk,
               float* __restrict__ qkout) {
  __shared__ float xs[16][512];
  int tid = threadIdx.x;
  int b = blockIdx.x >> 7;
  int t0 = (blockIdx.x & 127) << 4;
  const float* xb = x + ((size_t)(b * 2048 + t0)) * 512;
#pragma unroll
  for (int i = 0; i < 8; ++i) {
    int f = i * 256 + tid;
    int r = f >> 7, c4 = f & 127;
    *(float4*)&xs[r][c4 * 4] = *(const float4*)&xb[(size_t)r * 512 + c4 * 4];
  }
  __syncthreads();
  int c = tid & 63, r4 = tid >> 6;
  float a0 = 0.f, a1 = 0.f, a2 = 0.f, a3 = 0.f;
#pragma unroll 4
  for (int d = 0; d < 512; ++d) {
    float w = wqk[d * 64 + c];
    a0 += xs[r4][d] * w;
    a1 += xs[r4 + 4][d] * w;
    a2 += xs[r4 + 8][d] * w;
    a3 += xs[r4 + 12][d] * w;
  }
  float bias = (c < 32) ? bq[c] : bk[c - 32];
  size_t base = ((size_t)(b * 2048 + t0)) * 64 + c;
  qkout[base + (size_t)r4 * 64] = a0 + bias;
  qkout[base + (size_t)(r4 + 4) * 64] = a1 + bias;
  qkout[base + (size_t)(r4 + 8) * 64] = a2 + bias;
  qkout[base + (size_t)(r4 + 12) * 64] = a3 + bias;
}

// fused sim + top-4: block = 16 query rows; never materializes sim
__global__ __launch_bounds__(256)
void topk_kernel(const float* __restrict__ qkb, int* __restrict__ idxout) {
  __shared__ float qs[16][36];
  __shared__ float ks[128][36];
  __shared__ float mv[16][16][4];
  __shared__ int   mi[16][16][4];
  int tid = threadIdx.x;
  int b = blockIdx.x >> 7;
  int t0 = (blockIdx.x & 127) << 4;
  const float* qb = qkb + ((size_t)b * 2048) * 64;
  if (tid < 128) {
    int r = tid >> 3, c4 = tid & 7;
    *(float4*)&qs[r][c4 * 4] = *(const float4*)&qb[(size_t)(t0 + r) * 64 + c4 * 4];
  }
  __syncthreads();
  int tl = tid >> 4, sl = tid & 15;
  float qv[32];
#pragma unroll
  for (int kk = 0; kk < 32; ++kk) qv[kk] = qs[tl][kk];
  float v0 = -INFINITY, v1 = -INFINITY, v2 = -INFINITY, v3 = -INFINITY;
  int i0 = 0x7fffffff, i1 = 0x7fffffff, i2 = 0x7fffffff, i3 = 0x7fffffff;
  for (int s0 = 0; s0 < 2048; s0 += 128) {
    __syncthreads();
#pragma unroll
    for (int p = 0; p < 4; ++p) {
      int f = p * 256 + tid;
      int r = f >> 3, c4 = f & 7;
      *(float4*)&ks[r][c4 * 4] =
          *(const float4*)&qb[(size_t)(s0 + r) * 64 + 32 + c4 * 4];
    }
    __syncthreads();
#pragma unroll
    for (int j = 0; j < 8; ++j) {
      int srow = j * 16 + sl;
      float accv = 0.f;
#pragma unroll
      for (int k4 = 0; k4 < 8; ++k4) {
        float4 kv = *(const float4*)&ks[srow][k4 * 4];
        accv += qv[k4 * 4 + 0] * kv.x + qv[k4 * 4 + 1] * kv.y +
                qv[k4 * 4 + 2] * kv.z + qv[k4 * 4 + 3] * kv.w;
      }
      ins4(accv, s0 + srow, v0, i0, v1, i1, v2, i2, v3, i3);
    }
  }
  mv[tl][sl][0] = v0; mv[tl][sl][1] = v1; mv[tl][sl][2] = v2; mv[tl][sl][3] = v3;
  mi[tl][sl][0] = i0; mi[tl][sl][1] = i1; mi[tl][sl][2] = i2; mi[tl][sl][3] = i3;
  __syncthreads();
  if (tid < 16) {
    float w0 = -INFINITY, w1 = -INFINITY, w2 = -INFINITY, w3 = -INFINITY;
    int a0 = 0x7fffffff, a1 = 0x7fffffff, a2 = 0x7fffffff, a3 = 0x7fffffff;
    for (int ss = 0; ss < 16; ++ss)
#pragma unroll
      for (int q = 0; q < 4; ++q)
        ins4(mv[tid][ss][q], mi[tid][ss][q], w0, a0, w1, a1, w2, a2, w3, a3);
    int4 o; o.x = a0; o.y = a1; o.z = a2; o.w = a3;
    *(int4*)&idxout[((size_t)(b * 2048 + t0 + tid)) * 4] = o;
  }
}

__global__ __launch_bounds__(128)
void gather_kernel(const float* __restrict__ x, const int* __restrict__ idx,
                   float* __restrict__ gf, unsigned short* __restrict__ gb) {
  int bt = blockIdx.x;
  int b = bt >> 11;
  const int4 iv = *(const int4*)&idx[(size_t)bt * 4];
  int tid = threadIdx.x;
  const float* xb = x + ((size_t)b * 2048) * 512;
  float4 p0 = *(const float4*)&xb[(size_t)iv.x * 512 + tid * 4];
  float4 p1 = *(const float4*)&xb[(size_t)iv.y * 512 + tid * 4];
  float4 p2 = *(const float4*)&xb[(size_t)iv.z * 512 + tid * 4];
  float4 p3 = *(const float4*)&xb[(size_t)iv.w * 512 + tid * 4];
  float4 m;
  m.x = (p0.x + p1.x + p2.x + p3.x) * 0.25f;
  m.y = (p0.y + p1.y + p2.y + p3.y) * 0.25f;
  m.z = (p0.z + p1.z + p2.z + p3.z) * 0.25f;
  m.w = (p0.w + p1.w + p2.w + p3.w) * 0.25f;
  *(float4*)&gf[(size_t)bt * 512 + tid * 4] = m;
  ushort4 u; u.x = f2b(m.x); u.y = f2b(m.y); u.z = f2b(m.z); u.w = f2b(m.w);
  *(ushort4*)&gb[(size_t)bt * 512 + tid * 4] = u;
}

// ---------------- MFMA GEMM: C = A[MxK] * Bt[NxK]^T (+bias, epilogues) ------
// MODE 0: out bf16 = gelu(acc+bias)   MODE 1: out f32 = acc+bias+resid
// MODE 2: out f32 = acc+bias

template <int MODE>
__global__ __launch_bounds__(256, 2)
void gemm_bf16_k(const unsigned short* __restrict__ A,
                 const unsigned short* __restrict__ Bt,
                 const float* __restrict__ bias,
                 const float* __restrict__ resid,
                 void* __restrict__ outp, int M, int N, int K) {
  __shared__ unsigned short sA[128 * 32];
  __shared__ unsigned short sB[128 * 32];
  const int tid = threadIdx.x;
  const int lane = tid & 63, wave = tid >> 6;
  const int m0 = blockIdx.x * 128, n0 = blockIdx.y * 128;
  const int col16 = lane & 15, quad = lane >> 4;
  const int wm = wave >> 1, wn = wave & 1;
  f32x4v acc[4][4];
#pragma unroll
  for (int i = 0; i < 4; ++i)
#pragma unroll
    for (int j = 0; j < 4; ++j) {
      f32x4v z = {0.f, 0.f, 0.f, 0.f};
      acc[i][j] = z;
    }
  const int nkt = K >> 5;
  for (int kt = 0; kt < nkt; ++kt) {
    const int k0 = kt << 5;
#pragma unroll
    for (int p = 0; p < 2; ++p) {
      int f = p * 256 + tid;
      int row = f >> 2, q4 = f & 3;
      *(uint4*)&sA[row * 32 + q4 * 8] =
          *(const uint4*)(A + (size_t)(m0 + row) * K + k0 + q4 * 8);
      *(uint4*)&sB[row * 32 + q4 * 8] =
          *(const uint4*)(Bt + (size_t)(n0 + row) * K + k0 + q4 * 8);
    }
    __syncthreads();
    bf16x8 af[4], bfr[4];
#pragma unroll
    for (int i = 0; i < 4; ++i)
      af[i] = *(const bf16x8*)&sA[(wm * 64 + i * 16 + col16) * 32 + quad * 8];
#pragma unroll
    for (int j = 0; j < 4; ++j)
      bfr[j] = *(const bf16x8*)&sB[(wn * 64 + j * 16 + col16) * 32 + quad * 8];
#pragma unroll
    for (int i = 0; i < 4; ++i)
#pragma unroll
      for (int j = 0; j < 4; ++j)
        acc[i][j] = __builtin_amdgcn_mfma_f32_16x16x32_bf16(af[i], bfr[j],
                                                            acc[i][j], 0, 0, 0);
    __syncthreads();
  }
  float* outf = (float*)outp;
  unsigned short* outb = (unsigned short*)outp;
#pragma unroll
  for (int i = 0; i < 4; ++i)
#pragma unroll
    for (int j = 0; j < 4; ++j) {
      int col = n0 + wn * 64 + j * 16 + col16;
      float bs = bias[col];
#pragma unroll
      for (int r = 0; r < 4; ++r) {
        int row = m0 + wm * 64 + i * 16 + quad * 4 + r;
        float v = acc[i][j][r] + bs;
        if (MODE == 0) {
          outb[(size_t)row * N + col] = f2b(gelu_f(v));
        } else if (MODE == 1) {
          outf[(size_t)row * N + col] = v + resid[(size_t)row * N + col];
        } else {
          outf[(size_t)row * N + col] = v;
        }
      }
    }
}

// ---------------- LayerNorm (row-wise, fp32 -> bf16) ----------------

__global__ __launch_bounds__(128)
void ln_kernel(const float* __restrict__ ypre, const float* __restrict__ lg,
               const float* __restrict__ lb, unsigned short* __restrict__ yb) {
  int row = blockIdx.x, tid = threadIdx.x;
  float4 v = *(const float4*)&ypre[(size_t)row * 512 + tid * 4];
  float s = v.x + v.y + v.z + v.w;
  float sq = v.x * v.x + v.y * v.y + v.z * v.z + v.w * v.w;
#pragma unroll
  for (int off = 1; off < 64; off <<= 1) {
    s += __shfl_xor(s, off, 64);
    sq += __shfl_xor(sq, off, 64);
  }
  __shared__ float red[4];
  if ((tid & 63) == 0) { red[(tid >> 6) * 2] = s; red[(tid >> 6) * 2 + 1] = sq; }
  __syncthreads();
  float S = red[0] + red[2], SQ = red[1] + red[3];
  float mu = S * (1.f / 512.f);
  float var = SQ * (1.f / 512.f) - mu * mu;
  float rstd = rsqrtf(var + 1e-5f);
  float4 g4 = *(const float4*)&lg[tid * 4];
  float4 b4 = *(const float4*)&lb[tid * 4];
  ushort4 u;
  u.x = f2b((v.x - mu) * rstd * g4.x + b4.x);
  u.y = f2b((v.y - mu) * rstd * g4.y + b4.y);
  u.z = f2b((v.z - mu) * rstd * g4.z + b4.z);
  u.w = f2b((v.w - mu) * rstd * g4.w + b4.w);
  *(ushort4*)&yb[(size_t)row * 512 + tid * 4] = u;
}

// ---------------- System2: persistent serial scan --------------------------
// 8 teams x 32 WGs x 256 thr; blockIdx = g*8 + team.
// WG g owns u-slice [g*32,g*32+32) and mem-slice [g*16,g*16+16).
// LDS-resident fp32 weights (validated R3: no spill, no weight refetch).
// SYNC PROTOCOL (fence-free; the R1-R3 lesson): all cross-WG data+flags via
// RELAXED agent-scope atomics (sc0 sc1 -> LLC-homed, bypass L1/L2; LLC is the
// die-level coherence point). NO agent fences anywhere in the loop: an agent
// release fence = buffer_wbl2 (flush 4MiB XCD L2) and acquire = buffer_inv
// (invalidate it) -> that was the ~50us/step catastrophe in R1-R3.
// Ordering: producer data-stores -> __syncthreads() (drains vmcnt(0), so all
// stores reached the LLC) -> lane0 flag store (tag s+1). Consumer: poll flag
// relaxed until tag, __syncthreads(), then data loads (issue strictly after
// the observed flag; LLC already holds the data). Workgroup-scope acquire
// fence after polls = compiler barrier only (no cache ops).
// Tags s+1 never collide with the 0xAA harness poison; harness re-poisons
// d_ws before every replay, so no stale-tag hazard across launches.

__global__ __launch_bounds__(256)
void system2_kernel(const float* __restrict__ Wt1, const float* __restrict__ Wt2,
                    const float* __restrict__ bt2, const float* __restrict__ xpart,
                    float* __restrict__ slotbuf, float* __restrict__ membuf,
                    int* __restrict__ flagA, int* __restrict__ flagB,
                    float* __restrict__ memfinal) {
  __shared__ float WbT[32 * 516];   // [j][k], stride 516 for bank spread
  __shared__ float WtS[32 * 512];   // [u][d]
  __shared__ float memS[512];
  __shared__ float parts1[256];     // [c][j] = [8][32]
  __shared__ float red2[256];       // [w][dd] = [16][16]
  __shared__ float guL[32];

  const int t = threadIdx.x;
  const int team = blockIdx.x & 7;
  const int g = blockIdx.x >> 3;          // 0..31
  const int ucol0 = g << 5;
  const int mcol0 = g << 4;

  // ---- load weights into LDS (one-time) ----
  for (int idx = t; idx < 32 * 512; idx += 256) {
    int j = idx & 31, k = idx >> 5;
    WbT[j * 516 + k] = Wt1[(size_t)(512 + k) * 1024 + ucol0 + j];
  }
  for (int idx = t; idx < 32 * 512; idx += 256) {
    int u = idx >> 9, d = idx & 511;
    WtS[u * 512 + d] = Wt2[(size_t)(ucol0 + u) * 512 + d];
  }
  memS[t] = 0.f;
  memS[t + 256] = 0.f;
  const float bt2r = (t < 16) ? bt2[mcol0 + t] : 0.f;
  __syncthreads();

  const int j = t & 31, c = t >> 5;        // stage1 roles: col j, k-chunk c(8)
  const float* xp = xpart + (size_t)team * 2048 * 1024 + ucol0;
  float xv = (t < 32) ? xp[t] : 0.f;

  for (int s = 0; s < 2048; ++s) {
    const int par = s & 1;
    float* slot = slotbuf + ((size_t)(par * 8 + team) * 32) * 512;
    float* memb = membuf + (size_t)(par * 8 + team) * 512;
    int* flA = flagA + (par * 8 + team) * 32;
    int* flB = flagB + (par * 8 + team) * 32;
    const int tag = s + 1;

    float xnext = (t < 32 && s < 2047) ? xp[(size_t)(s + 1) * 1024 + t] : 0.f;

    // ---- stage1: u[ucol0+j] partial over k-chunk c (64 k), float4 LDS ----
    {
      const float* wrow = &WbT[j * 516 + c * 64];
      const float* mrow = &memS[c * 64];
      float p1 = 0.f;
#pragma unroll
      for (int i = 0; i < 64; i += 4) {
        float4 wv = *(const float4*)&wrow[i];
        float4 mv = *(const float4*)&mrow[i];
        p1 += wv.x * mv.x + wv.y * mv.y + wv.z * mv.z + wv.w * mv.w;
      }
      parts1[c * 32 + j] = p1;
    }
    __syncthreads();
    if (t < 32) {
      float u = xv;   // xpart includes xt@Wt1[:512] + bt1
#pragma unroll
      for (int cc = 0; cc < 8; ++cc) u += parts1[cc * 32 + t];
      guL[t] = gelu_f(u);
    }
    __syncthreads();

    // ---- stage2: partial prop over this WG's 32 u-rows; 2 cols/thread ----
    {
      const int d2 = t << 1;
      float px = 0.f, py = 0.f;
#pragma unroll
      for (int u = 0; u < 32; ++u) {
        float gv = guL[u];
        float2 wv = *(const float2*)&WtS[u * 512 + d2];
        px += gv * wv.x;
        py += gv * wv.y;
      }
      union { float2 f2; ull u64; } cv;
      cv.f2 = make_float2(px, py);
      __hip_atomic_store((ull*)&slot[g * 512 + d2], cv.u64, __ATOMIC_RELAXED,
                         __HIP_MEMORY_SCOPE_AGENT);
    }
    // barrier drains vmcnt(0): all 256 threads' slot stores are at the LLC
    __syncthreads();
    if (t == 0)
      __hip_atomic_store(&flA[g], tag, __ATOMIC_RELAXED,
                         __HIP_MEMORY_SCOPE_AGENT);
    // ---- poll A: all 32 slots ready (relaxed loads; no cache ops) ----
    if (t < 64) {
      int f = (t < 32) ? 0 : tag;
      const int* fp = &flA[t < 32 ? t : 0];
      while (true) {
        if (t < 32 && f != tag)
          f = __hip_atomic_load(fp, __ATOMIC_RELAXED, __HIP_MEMORY_SCOPE_AGENT);
        if (__ballot(f == tag) == ~0ull) break;
        __builtin_amdgcn_s_sleep(1);
      }
    }
    __syncthreads();
    __builtin_amdgcn_fence(__ATOMIC_ACQUIRE, "workgroup");  // compiler barrier

    // ---- reduce 32 partials for own 16 mem-cols ----
    {
      const int w = t >> 4, dd = t & 15;
      float v1 = __hip_atomic_load(&slot[w * 512 + mcol0 + dd], __ATOMIC_RELAXED,
                                   __HIP_MEMORY_SCOPE_AGENT);
      float v2 = __hip_atomic_load(&slot[(w + 16) * 512 + mcol0 + dd],
                                   __ATOMIC_RELAXED, __HIP_MEMORY_SCOPE_AGENT);
      red2[w * 16 + dd] = v1 + v2;
    }
    __syncthreads();
    if (t < 16) {
      float prop = bt2r;
#pragma unroll
      for (int w = 0; w < 16; ++w) prop += red2[w * 16 + t];
      float gate = 1.f / (1.f + __expf(-prop));
      float mnew = memS[mcol0 + t] * (1.f - gate) + prop * gate;
      __hip_atomic_store(&memb[mcol0 + t], mnew, __ATOMIC_RELAXED,
                         __HIP_MEMORY_SCOPE_AGENT);
    }
    // barrier drains vmcnt(0): mem-slice stores are at the LLC
    __syncthreads();
    if (t == 0)
      __hip_atomic_store(&flB[g], tag, __ATOMIC_RELAXED,
                         __HIP_MEMORY_SCOPE_AGENT);
    // ---- poll B: all 32 mem slices ready ----
    if (t < 64) {
      int f = (t < 32) ? 0 : tag;
      const int* fp = &flB[t < 32 ? t : 0];
      while (true) {
        if (t < 32 && f != tag)
          f = __hip_atomic_load(fp, __ATOMIC_RELAXED, __HIP_MEMORY_SCOPE_AGENT);
        if (__ballot(f == tag) == ~0ull) break;
        __builtin_amdgcn_s_sleep(1);
      }
    }
    __syncthreads();
    __builtin_amdgcn_fence(__ATOMIC_ACQUIRE, "workgroup");  // compiler barrier

    // ---- read full mem (512 floats as 256 ull by t<128) ----
    if (t < 128) {
      union { float2 f2; ull u64; } a, b;
      a.u64 = __hip_atomic_load((ull*)&memb[t * 4], __ATOMIC_RELAXED,
                                __HIP_MEMORY_SCOPE_AGENT);
      b.u64 = __hip_atomic_load((ull*)&memb[t * 4 + 2], __ATOMIC_RELAXED,
                                __HIP_MEMORY_SCOPE_AGENT);
      memS[t * 4 + 0] = a.f2.x;
      memS[t * 4 + 1] = a.f2.y;
      memS[t * 4 + 2] = b.f2.x;
      memS[t * 4 + 3] = b.f2.y;
    }
    xv = xnext;
    __syncthreads();
  }

  if (g == 0 && t < 128)
    *(float4*)&memfinal[(size_t)team * 512 + t * 4] = *(float4*)&memS[t * 4];
}

// ---------------- output GEMV ----------------

__global__ __launch_bounds__(256)
void out_gemv_kernel(const float* __restrict__ memf, const float* __restrict__ Wo,
                     const float* __restrict__ bo, float* __restrict__ out) {
  int gid = blockIdx.x * 256 + threadIdx.x;   // 4096 total
  int b = gid >> 9, d = gid & 511;
  const float* mb = memf + (size_t)b * 512;
  float acc = bo[d];
#pragma unroll 8
  for (int k = 0; k < 512; ++k) acc += mb[k] * Wo[(size_t)k * 512 + d];
  out[gid] = acc;
}

// ---------------- launch ----------------

extern "C" void kernel_launch(void* const* d_in, const int* in_sizes, int n_in,
                              void* d_out, int out_size, void* d_ws, size_t ws_size,
                              hipStream_t stream) {
  const float* x   = (const float*)d_in[0];
  const float* Wq  = (const float*)d_in[1];
  const float* bq  = (const float*)d_in[2];
  const float* Wk  = (const float*)d_in[3];
  const float* bk  = (const float*)d_in[4];
  const float* W1  = (const float*)d_in[5];
  const float* b1  = (const float*)d_in[6];
  const float* W2  = (const float*)d_in[7];
  const float* b2  = (const float*)d_in[8];
  const float* lng = (const float*)d_in[9];
  const float* lnb = (const float*)d_in[10];
  const float* Wt1 = (const float*)d_in[11];
  const float* bt1 = (const float*)d_in[12];
  const float* Wt2 = (const float*)d_in[13];
  const float* bt2 = (const float*)d_in[14];
  const float* Wo  = (const float*)d_in[15];
  const float* bo  = (const float*)d_in[16];
  float* out = (float*)d_out;

  char* ws = (char*)d_ws;
  size_t off = 0;
  auto alloc = [&](size_t bytes) -> void* {
    void* p = ws + off;
    off += (bytes + 255) & ~(size_t)255;
    return p;
  };
  float* qk             = (float*)alloc(8ull * 2048 * 64 * 4);
  int* idxb             = (int*)alloc(8ull * 2048 * 4 * 4);
  float* gathf          = (float*)alloc(16384ull * 512 * 4);
  unsigned short* gathb = (unsigned short*)alloc(16384ull * 512 * 2);
  unsigned short* h1b   = (unsigned short*)alloc(16384ull * 1024 * 2);
  float* ypre           = (float*)alloc(16384ull * 512 * 4);
  unsigned short* yb    = (unsigned short*)alloc(16384ull * 512 * 2);
  float* xpart          = (float*)alloc(16384ull * 1024 * 4);
  unsigned short* w1t   = (unsigned short*)alloc(1024ull * 512 * 2);
  unsigned short* w2t   = (unsigned short*)alloc(512ull * 1024 * 2);
  unsigned short* wt1t  = (unsigned short*)alloc(1024ull * 512 * 2);
  float* wqkb           = (float*)alloc(512ull * 64 * 4);
  float* slotbuf        = (float*)alloc(2ull * 8 * 32 * 512 * 4);  // 1 MB
  float* membuf         = (float*)alloc(2ull * 8 * 512 * 4);
  int* flagA            = (int*)alloc(2ull * 8 * 32 * 4);
  int* flagB            = (int*)alloc(2ull * 8 * 32 * 4);
  float* memf           = (float*)alloc(8ull * 512 * 4);
  if (off > ws_size) return;  // workspace too small -> visible bench failure

  wqk_kernel<<<128, 256, 0, stream>>>(Wq, Wk, wqkb);
  transpose_bf16_kernel<<<dim3(16, 32), 256, 0, stream>>>(W1, w1t, 512, 1024);
  transpose_bf16_kernel<<<dim3(32, 16), 256, 0, stream>>>(W2, w2t, 1024, 512);
  transpose_bf16_kernel<<<dim3(16, 32), 256, 0, stream>>>(Wt1, wt1t, 512, 1024);

  qk_kernel<<<1024, 256, 0, stream>>>(x, wqkb, bq, bk, qk);
  topk_kernel<<<1024, 256, 0, stream>>>(qk, idxb);
  gather_kernel<<<16384, 128, 0, stream>>>(x, idxb, gathf, gathb);

  gemm_bf16_k<0><<<dim3(128, 8), 256, 0, stream>>>(gathb, w1t, b1, nullptr, h1b,
                                                   16384, 1024, 512);
  gemm_bf16_k<1><<<dim3(128, 4), 256, 0, stream>>>(h1b, w2t, b2, gathf, ypre,
                                                   16384, 512, 1024);
  ln_kernel<<<16384, 128, 0, stream>>>(ypre, lng, lnb, yb);
  gemm_bf16_k<2><<<dim3(128, 8), 256, 0, stream>>>(yb, wt1t, bt1, nullptr, xpart,
                                                   16384, 1024, 512);

  system2_kernel<<<256, 256, 0, stream>>>(Wt1, Wt2, bt2, xpart, slotbuf, membuf,
                                          flagA, flagB, memf);
  out_gemv_kernel<<<16, 256, 0, stream>>>(memf, Wo, bo, out);
}